// Round 6
// baseline (181.196 us; speedup 1.0000x reference)
//
#include <hip/hip_runtime.h>

#define B 4
#define N 1024
#define K 100
#define F 42
#define H 64

#define APB 64          // atoms per block (lane = local atom)
#define NW  8           // waves per block
#define IPW (H / NW)    // hidden units owned per wave = 8

// ---------------------------------------------------------------------------
// Kernel 1 (v5): MLP fwd + input grad, lane = ATOM.
// All weight indices are wave-uniform -> compiler emits scalar s_load
// (constant-cache, dwordx-vectorized over contiguous hidden runs). LDS only
// holds the small h1/g2/g1 exchanges; each is read ONCE into registers in
// 16-chunks, never re-read. Block = 64 atoms x 8 waves (wave owns 8 units).
// ---------------------------------------------------------------------------
__global__ __launch_bounds__(512) void mlp_kernel(
    const float* __restrict__ image,
    const float* __restrict__ W1, const float* __restrict__ b1,
    const float* __restrict__ W2, const float* __restrict__ b2,
    const float* __restrict__ W3, const float* __restrict__ b3,
    float* __restrict__ Ei, float* __restrict__ dE)
{
    __shared__ float xsh[APB][F + 1];   // pad 43: (11*lane+f)%32 permutes banks
    __shared__ float h1sh[H][APB];      // [j][atom]: fixed j -> 2 lanes/bank, free
    __shared__ float g2sh[H][APB];
    __shared__ float g1sh[H][APB];
    __shared__ float esh[NW][APB];
    __shared__ float dsh[APB][F + 1];   // pad 43

    const int tid  = threadIdx.x;
    const int lane = tid & 63;          // local atom
    const int w    = tid >> 6;          // wave id 0..7
    const int a0   = blockIdx.x * APB;  // 64 blocks * 64 atoms = 4096
    const int i0   = w * IPW;           // my hidden-unit base

    // stage image rows (coalesced global -> LDS)
    for (int idx = tid; idx < APB * F; idx += 512) {
        const int a = idx / F, f = idx - a * F;
        xsh[a][f] = image[(size_t)a0 * F + idx];
    }
    __syncthreads();

    // x into registers (42 conflict-free b32 reads)
    float x[F];
    #pragma unroll
    for (int f = 0; f < F; ++f) x[f] = xsh[lane][f];

    // ---- layer 1: a1[i0+ii] = b1 + sum_f x[f] * W1[f][i0+ii] (W uniform) ----
    float acc[IPW];
    #pragma unroll
    for (int ii = 0; ii < IPW; ++ii) acc[ii] = b1[i0 + ii];
    #pragma unroll 6
    for (int f = 0; f < F; ++f) {
        #pragma unroll
        for (int ii = 0; ii < IPW; ++ii)
            acc[ii] = fmaf(x[f], W1[f * H + i0 + ii], acc[ii]);
    }
    float h1l[IPW];
    #pragma unroll
    for (int ii = 0; ii < IPW; ++ii) {
        h1l[ii] = tanhf(acc[ii]);
        h1sh[i0 + ii][lane] = h1l[ii];
    }
    __syncthreads();

    // ---- layer 2: chunk h1 into regs (read once), W2 runs contiguous ----
    #pragma unroll
    for (int ii = 0; ii < IPW; ++ii) acc[ii] = b2[i0 + ii];
    #pragma unroll
    for (int jc = 0; jc < H / 16; ++jc) {
        float hv[16];
        #pragma unroll
        for (int t = 0; t < 16; ++t) hv[t] = h1sh[jc * 16 + t][lane];
        #pragma unroll
        for (int t = 0; t < 16; ++t)
            #pragma unroll
            for (int ii = 0; ii < IPW; ++ii)
                acc[ii] = fmaf(hv[t], W2[(jc * 16 + t) * H + i0 + ii], acc[ii]);
    }

    // h2, Ei partial, g2
    float ep = 0.0f;
    #pragma unroll
    for (int ii = 0; ii < IPW; ++ii) {
        const float h2 = tanhf(acc[ii]);
        const float w3 = W3[i0 + ii];
        ep = fmaf(h2, w3, ep);
        g2sh[i0 + ii][lane] = w3 * (1.0f - h2 * h2);
    }
    esh[w][lane] = ep;
    __syncthreads();

    if (w == 0) {
        float e = b3[0];
        #pragma unroll
        for (int q = 0; q < NW; ++q) e += esh[q][lane];
        Ei[a0 + lane] = e;
    }

    // ---- g1[j] = (1-h1[j]^2) * sum_i W2[j][i] * g2[i], my 8 j's ----
    float s[IPW];
    #pragma unroll
    for (int jj = 0; jj < IPW; ++jj) s[jj] = 0.0f;
    #pragma unroll
    for (int ic = 0; ic < H / 16; ++ic) {
        float gv[16];
        #pragma unroll
        for (int t = 0; t < 16; ++t) gv[t] = g2sh[ic * 16 + t][lane];
        #pragma unroll
        for (int jj = 0; jj < IPW; ++jj)
            #pragma unroll
            for (int t = 0; t < 16; ++t)
                s[jj] = fmaf(gv[t], W2[(i0 + jj) * H + ic * 16 + t], s[jj]);
    }
    #pragma unroll
    for (int jj = 0; jj < IPW; ++jj)
        g1sh[i0 + jj][lane] = s[jj] * (1.0f - h1l[jj] * h1l[jj]);
    __syncthreads();

    // ---- dE[f] = sum_j W1[f][j] * g1[j]; waves split f: sizes {6,6,6,6,5,5,5,3} ----
    {
        const int fbase = (w < 4) ? (w * 6) : (24 + (w - 4) * 5);  // 0,6,12,18,24,29,34,39
        const int nf    = (w < 4) ? 6 : ((w < 7) ? 5 : 3);
        float s2[6];
        #pragma unroll
        for (int q = 0; q < 6; ++q) s2[q] = 0.0f;
        #pragma unroll
        for (int jc = 0; jc < H / 16; ++jc) {
            float gv[16];
            #pragma unroll
            for (int t = 0; t < 16; ++t) gv[t] = g1sh[jc * 16 + t][lane];
            #pragma unroll
            for (int q = 0; q < 6; ++q) {
                if (q < nf) {
                    #pragma unroll
                    for (int t = 0; t < 16; ++t)
                        s2[q] = fmaf(gv[t], W1[(fbase + q) * H + jc * 16 + t], s2[q]);
                }
            }
        }
        #pragma unroll
        for (int q = 0; q < 6; ++q)
            if (q < nf) dsh[lane][fbase + q] = s2[q];
    }
    __syncthreads();

    // coalesced write-out of dE
    for (int idx = tid; idx < APB * F; idx += 512) {
        const int a = idx / F, f = idx - a * F;
        dE[(size_t)a0 * F + idx] = dsh[a][f];
    }
}

// ---------------------------------------------------------------------------
// Kernel 2: Force (R5 structure, unchanged) + Etot tail blocks.
// ---------------------------------------------------------------------------
__global__ __launch_bounds__(256) void force_kernel(
    const float* __restrict__ dE, const float* __restrict__ dfeat,
    const int* __restrict__ neighbor, const float* __restrict__ Ei,
    float* __restrict__ force, float* __restrict__ Etot)
{
    __shared__ int   nsh[K];
    __shared__ float red[4][3];

    const int tid  = threadIdx.x;
    const int bid  = blockIdx.x;
    const int lane = tid & 63, wave = tid >> 6;

    if (bid >= B * N) {                    // ---- Etot tail blocks ----
        const int b = bid - B * N;
        float s = 0.0f;
        for (int i = tid; i < N; i += 256) s += Ei[b * N + i];
        #pragma unroll
        for (int off = 32; off > 0; off >>= 1) s += __shfl_down(s, off);
        if (lane == 0) red[wave][0] = s;
        __syncthreads();
        if (tid == 0)
            Etot[b] = (red[0][0] + red[1][0]) + (red[2][0] + red[3][0]);
        return;
    }

    const int bn = bid;
    const int b  = bn >> 10;               // N = 1024

    if (tid < K) nsh[tid] = neighbor[bn * K + tid];
    __syncthreads();

    const float* df  = dfeat + (size_t)bn * (K * F * 3);
    const float* dEb = dE + (size_t)b * (N * F);

    float fx = 0.0f, fy = 0.0f, fz = 0.0f;
    for (int p = tid; p < K * F; p += 256) {
        const int k  = p / F;
        const int f  = p - k * F;
        const int nb = nsh[k];
        const float de = (nb > 0) ? dEb[(nb - 1) * F + f] : 0.0f;
        const int base = p * 3;
        fx = fmaf(de, df[base + 0], fx);
        fy = fmaf(de, df[base + 1], fy);
        fz = fmaf(de, df[base + 2], fz);
    }

    #pragma unroll
    for (int off = 32; off > 0; off >>= 1) {
        fx += __shfl_down(fx, off);
        fy += __shfl_down(fy, off);
        fz += __shfl_down(fz, off);
    }
    if (lane == 0) { red[wave][0] = fx; red[wave][1] = fy; red[wave][2] = fz; }
    __syncthreads();
    if (tid == 0) {
        force[bn * 3 + 0] = (red[0][0] + red[1][0]) + (red[2][0] + red[3][0]);
        force[bn * 3 + 1] = (red[0][1] + red[1][1]) + (red[2][1] + red[3][1]);
        force[bn * 3 + 2] = (red[0][2] + red[1][2]) + (red[2][2] + red[3][2]);
    }
}

extern "C" void kernel_launch(void* const* d_in, const int* in_sizes, int n_in,
                              void* d_out, int out_size, void* d_ws, size_t ws_size,
                              hipStream_t stream)
{
    const float* image    = (const float*)d_in[0];
    const float* dfeat    = (const float*)d_in[1];
    const int*   neighbor = (const int*)d_in[2];
    // d_in[3] Egroup_weight, d_in[4] divider: unused by the reference outputs
    const float* W1 = (const float*)d_in[5];
    const float* b1 = (const float*)d_in[6];
    const float* W2 = (const float*)d_in[7];
    const float* b2 = (const float*)d_in[8];
    const float* W3 = (const float*)d_in[9];
    const float* b3 = (const float*)d_in[10];

    float* out   = (float*)d_out;
    float* Etot  = out;                 // [B]
    float* Ei    = out + B;             // [B,N]
    float* Force = out + B + B * N;     // [B,N,3]
    float* dE    = (float*)d_ws;        // [B,N,F]

    mlp_kernel<<<(B * N) / APB, 512, 0, stream>>>(image, W1, b1, W2, b2, W3, b3, Ei, dE);
    force_kernel<<<B * N + B, 256, 0, stream>>>(dE, dfeat, neighbor, Ei, Force, Etot);
}

// Round 7
// 49.673 us; speedup vs baseline: 3.6478x; 3.6478x over previous
//
#include <hip/hip_runtime.h>

#define B 4
#define N 1024
#define K 100
#define F 42
#define H 64

#define APW 4                 // atoms per wave
#define NWV 4                 // waves per block
#define APB (APW * NWV)       // 16 atoms per block -> grid 256 (1 block/CU)
#define PW  68                // W row pad: >=64, %32==4 -> b128 row reads bank-spread, 272B rows 16B-aligned
#define PX  44                // xsh row pad (broadcast-only reads; 176B rows 16B-aligned)

typedef float f32x4 __attribute__((ext_vector_type(4)));

// ---------------------------------------------------------------------------
// Kernel 1 (v7): MLP fwd + input grad. lane = hidden unit, wave = 4 atoms.
// LDS-op minimized: W staged once/block; W read once per 4 FMAs; activation
// broadcasts via uniform ds_read_b128; backward W-row reads via per-lane
// ds_read_b128 (row stride 68 floats -> start bank 4*lane%32, even spread).
// One __syncthreads (after staging); the rest is wave-local lockstep.
// ---------------------------------------------------------------------------
__global__ __launch_bounds__(256) void mlp_kernel(
    const float* __restrict__ image,
    const float* __restrict__ W1, const float* __restrict__ b1,
    const float* __restrict__ W2, const float* __restrict__ b2,
    const float* __restrict__ W3, const float* __restrict__ b3,
    float* __restrict__ Ei, float* __restrict__ dE)
{
    __shared__ __align__(16) float W1s[F][PW];          // W1[f][i], 11.4 KB
    __shared__ __align__(16) float W2s[H][PW];          // W2[j][i], 17.4 KB
    __shared__ __align__(16) float xsh[APB][PX];        // 2.8 KB
    __shared__ __align__(16) float h1sh[NWV][APW][H];   // 4 KB
    __shared__ __align__(16) float g2sh[NWV][APW][H];   // 4 KB
    __shared__ __align__(16) float g1sh[NWV][APW][H];   // 4 KB

    const int tid  = threadIdx.x;
    const int lane = tid & 63;
    const int wv   = tid >> 6;
    const int a0   = blockIdx.x * APB;
    const int aw   = a0 + wv * APW;

    // coalesced staging (H == 64 -> idx>>6 / idx&63)
    for (int idx = tid; idx < F * H; idx += 256)
        W1s[idx >> 6][idx & 63] = W1[idx];
    for (int idx = tid; idx < H * H; idx += 256)
        W2s[idx >> 6][idx & 63] = W2[idx];
    for (int idx = tid; idx < APB * F; idx += 256) {
        const int a = idx / F, f = idx - a * F;
        xsh[a][f] = image[(size_t)a0 * F + idx];
    }
    __syncthreads();

    // ---- layer 1: acc[a] = b1 + sum_f x[a][f] * W1[f][lane] ----
    float acc[APW];
    {
        const float bb = b1[lane];
        #pragma unroll
        for (int a = 0; a < APW; ++a) acc[a] = bb;
    }
    #pragma unroll
    for (int fc = 0; fc < 10; ++fc) {               // f = 4fc .. 4fc+3
        float wv4[4];
        #pragma unroll
        for (int t = 0; t < 4; ++t) wv4[t] = W1s[4 * fc + t][lane];   // stride-1 lanes: free
        #pragma unroll
        for (int a = 0; a < APW; ++a) {
            const f32x4 xv = *(const f32x4*)&xsh[wv * APW + a][4 * fc];  // uniform b128 bcast
            #pragma unroll
            for (int t = 0; t < 4; ++t) acc[a] = fmaf(xv[t], wv4[t], acc[a]);
        }
    }
    #pragma unroll
    for (int f = 40; f < F; ++f) {                  // tail f = 40,41
        const float w = W1s[f][lane];
        #pragma unroll
        for (int a = 0; a < APW; ++a) acc[a] = fmaf(xsh[wv * APW + a][f], w, acc[a]);
    }
    float h1l[APW];
    #pragma unroll
    for (int a = 0; a < APW; ++a) {
        h1l[a] = tanhf(acc[a]);
        h1sh[wv][a][lane] = h1l[a];
    }
    __builtin_amdgcn_wave_barrier();                // wave-local exchange; no s_barrier

    // ---- layer 2: acc[a] = b2 + sum_j h1[a][j] * W2[j][lane] ----
    {
        const float bb = b2[lane];
        #pragma unroll
        for (int a = 0; a < APW; ++a) acc[a] = bb;
    }
    #pragma unroll
    for (int jc = 0; jc < H / 4; ++jc) {
        float wv4[4];
        #pragma unroll
        for (int t = 0; t < 4; ++t) wv4[t] = W2s[4 * jc + t][lane];
        #pragma unroll
        for (int a = 0; a < APW; ++a) {
            const f32x4 hv = *(const f32x4*)&h1sh[wv][a][4 * jc];
            #pragma unroll
            for (int t = 0; t < 4; ++t) acc[a] = fmaf(hv[t], wv4[t], acc[a]);
        }
    }
    const float w3 = W3[lane];
    const float bias3 = b3[0];
    #pragma unroll
    for (int a = 0; a < APW; ++a) {
        const float h2 = tanhf(acc[a]);
        g2sh[wv][a][lane] = w3 * (1.0f - h2 * h2);
        float t = h2 * w3;
        #pragma unroll
        for (int off = 32; off > 0; off >>= 1) t += __shfl_down(t, off);
        if (lane == 0) Ei[aw + a] = t + bias3;
    }
    __builtin_amdgcn_wave_barrier();

    // ---- g1[lane] = (1-h1^2) * sum_i W2[lane][i] * g2[i] (b128 row reads) ----
    float s[APW] = {0.f, 0.f, 0.f, 0.f};
    #pragma unroll
    for (int ic = 0; ic < H / 4; ++ic) {
        const f32x4 wr = *(const f32x4*)&W2s[lane][4 * ic];   // per-lane b128, bank-spread
        #pragma unroll
        for (int a = 0; a < APW; ++a) {
            const f32x4 gv = *(const f32x4*)&g2sh[wv][a][4 * ic];
            #pragma unroll
            for (int t = 0; t < 4; ++t) s[a] = fmaf(wr[t], gv[t], s[a]);
        }
    }
    #pragma unroll
    for (int a = 0; a < APW; ++a)
        g1sh[wv][a][lane] = s[a] * (1.0f - h1l[a] * h1l[a]);
    __builtin_amdgcn_wave_barrier();

    // ---- dE[f=lane] = sum_i W1[lane][i] * g1[i] (b128 row reads) ----
    if (lane < F) {
        float dx[APW] = {0.f, 0.f, 0.f, 0.f};
        #pragma unroll
        for (int ic = 0; ic < H / 4; ++ic) {
            const f32x4 wr = *(const f32x4*)&W1s[lane][4 * ic];
            #pragma unroll
            for (int a = 0; a < APW; ++a) {
                const f32x4 gv = *(const f32x4*)&g1sh[wv][a][4 * ic];
                #pragma unroll
                for (int t = 0; t < 4; ++t) dx[a] = fmaf(wr[t], gv[t], dx[a]);
            }
        }
        #pragma unroll
        for (int a = 0; a < APW; ++a)
            dE[(size_t)(aw + a) * F + lane] = dx[a];
    }
}

// ---------------------------------------------------------------------------
// Kernel 2: Force (R5 structure, unchanged) + Etot tail blocks.
// ---------------------------------------------------------------------------
__global__ __launch_bounds__(256) void force_kernel(
    const float* __restrict__ dE, const float* __restrict__ dfeat,
    const int* __restrict__ neighbor, const float* __restrict__ Ei,
    float* __restrict__ force, float* __restrict__ Etot)
{
    __shared__ int   nsh[K];
    __shared__ float red[4][3];

    const int tid  = threadIdx.x;
    const int bid  = blockIdx.x;
    const int lane = tid & 63, wave = tid >> 6;

    if (bid >= B * N) {                    // ---- Etot tail blocks ----
        const int b = bid - B * N;
        float s = 0.0f;
        for (int i = tid; i < N; i += 256) s += Ei[b * N + i];
        #pragma unroll
        for (int off = 32; off > 0; off >>= 1) s += __shfl_down(s, off);
        if (lane == 0) red[wave][0] = s;
        __syncthreads();
        if (tid == 0)
            Etot[b] = (red[0][0] + red[1][0]) + (red[2][0] + red[3][0]);
        return;
    }

    const int bn = bid;
    const int b  = bn >> 10;               // N = 1024

    if (tid < K) nsh[tid] = neighbor[bn * K + tid];
    __syncthreads();

    const float* df  = dfeat + (size_t)bn * (K * F * 3);
    const float* dEb = dE + (size_t)b * (N * F);

    float fx = 0.0f, fy = 0.0f, fz = 0.0f;
    for (int p = tid; p < K * F; p += 256) {
        const int k  = p / F;
        const int f  = p - k * F;
        const int nb = nsh[k];
        const float de = (nb > 0) ? dEb[(nb - 1) * F + f] : 0.0f;
        const int base = p * 3;
        fx = fmaf(de, df[base + 0], fx);
        fy = fmaf(de, df[base + 1], fy);
        fz = fmaf(de, df[base + 2], fz);
    }

    #pragma unroll
    for (int off = 32; off > 0; off >>= 1) {
        fx += __shfl_down(fx, off);
        fy += __shfl_down(fy, off);
        fz += __shfl_down(fz, off);
    }
    if (lane == 0) { red[wave][0] = fx; red[wave][1] = fy; red[wave][2] = fz; }
    __syncthreads();
    if (tid == 0) {
        force[bn * 3 + 0] = (red[0][0] + red[1][0]) + (red[2][0] + red[3][0]);
        force[bn * 3 + 1] = (red[0][1] + red[1][1]) + (red[2][1] + red[3][1]);
        force[bn * 3 + 2] = (red[0][2] + red[1][2]) + (red[2][2] + red[3][2]);
    }
}

extern "C" void kernel_launch(void* const* d_in, const int* in_sizes, int n_in,
                              void* d_out, int out_size, void* d_ws, size_t ws_size,
                              hipStream_t stream)
{
    const float* image    = (const float*)d_in[0];
    const float* dfeat    = (const float*)d_in[1];
    const int*   neighbor = (const int*)d_in[2];
    // d_in[3] Egroup_weight, d_in[4] divider: unused by the reference outputs
    const float* W1 = (const float*)d_in[5];
    const float* b1 = (const float*)d_in[6];
    const float* W2 = (const float*)d_in[7];
    const float* b2 = (const float*)d_in[8];
    const float* W3 = (const float*)d_in[9];
    const float* b3 = (const float*)d_in[10];

    float* out   = (float*)d_out;
    float* Etot  = out;                 // [B]
    float* Ei    = out + B;             // [B,N]
    float* Force = out + B + B * N;     // [B,N,3]
    float* dE    = (float*)d_ws;        // [B,N,F]

    mlp_kernel<<<(B * N) / APB, 256, 0, stream>>>(image, W1, b1, W2, b2, W3, b3, Ei, dE);
    force_kernel<<<B * N + B, 256, 0, stream>>>(dE, dfeat, neighbor, Ei, Force, Etot);
}